// Round 1
// baseline (423.077 us; speedup 1.0000x reference)
//
#include <hip/hip_runtime.h>

// B=2, S=2048, D=1024, H=16, DK=64.  BH = 32, M = B*S = 4096.
// Threshold is ~2% of |ref|max -> bf16 MFMA with fp32 accumulation is safe.

typedef float f32x4 __attribute__((ext_vector_type(4)));
typedef short short8 __attribute__((ext_vector_type(8)));

__device__ __forceinline__ unsigned short f2bf(float f) {
    unsigned u = __builtin_bit_cast(unsigned, f);
    u += 0x7fffu + ((u >> 16) & 1u);          // round-to-nearest-even
    return (unsigned short)(u >> 16);
}

// ---------------------------------------------------------------------------
// Kernel 1: fused QKV projection.  z = blockIdx.z selects (X, W, b, out).
//   C[4096,1024] = X[4096,1024] @ W[1024,1024] + bias, output bf16.
//   Q,K stored [B,H,S,DK]; V stored transposed [B,H,DK,S] so attention can
//   load V B-fragments contiguously from global.
// 64x64 tile / workgroup, 4 waves x (16m x 64n), K-step 32.
// LDS rows padded to 40 elems (80 B) -> 16B-aligned ds_*_b128, spread banks.
// ---------------------------------------------------------------------------
__global__ __launch_bounds__(256) void qkv_gemm(
    const float* __restrict__ Xq, const float* __restrict__ Xk, const float* __restrict__ Xv,
    const float* __restrict__ Wq, const float* __restrict__ Wk, const float* __restrict__ Wv,
    const float* __restrict__ bq, const float* __restrict__ bk, const float* __restrict__ bv,
    unsigned short* __restrict__ qo, unsigned short* __restrict__ ko, unsigned short* __restrict__ vo)
{
    const int z = blockIdx.z;
    const float* X    = (z == 0) ? Xq : (z == 1) ? Xk : Xv;
    const float* W    = (z == 0) ? Wq : (z == 1) ? Wk : Wv;
    const float* bias = (z == 0) ? bq : (z == 1) ? bk : bv;
    unsigned short* out = (z == 0) ? qo : (z == 1) ? ko : vo;

    __shared__ unsigned short As[64][40];   // [m][k], padded
    __shared__ unsigned short Bs[64][40];   // [n][k] (W transposed), padded

    const int tid  = threadIdx.x;
    const int wave = tid >> 6;
    const int lane = tid & 63;
    const int l15  = lane & 15;
    const int quad = lane >> 4;

    const int mbase = blockIdx.x * 64;
    const int nbase = blockIdx.y * 64;

    f32x4 acc[4] = {{0.f,0.f,0.f,0.f},{0.f,0.f,0.f,0.f},{0.f,0.f,0.f,0.f},{0.f,0.f,0.f,0.f}};

    // staging assignments (256 threads, 2048 elems per tile -> 8/thread)
    const int am  = tid >> 2;         // 0..63  A row
    const int ak  = (tid & 3) << 3;   // 0,8,16,24
    const int bn  = tid & 63;         // 0..63  B row (= output feature n)
    const int bk0 = (tid >> 6) << 3;  // 0,8,16,24

    for (int k0 = 0; k0 < 1024; k0 += 32) {
        __syncthreads();
        // ---- stage A: X[mbase+am][k0+ak .. +8], fp32 -> bf16
        {
            const float* xa = X + (size_t)(mbase + am) * 1024 + k0 + ak;
            float4 x0 = *(const float4*)xa;
            float4 x1 = *(const float4*)(xa + 4);
            short8 a8;
            a8[0] = (short)f2bf(x0.x); a8[1] = (short)f2bf(x0.y);
            a8[2] = (short)f2bf(x0.z); a8[3] = (short)f2bf(x0.w);
            a8[4] = (short)f2bf(x1.x); a8[5] = (short)f2bf(x1.y);
            a8[6] = (short)f2bf(x1.z); a8[7] = (short)f2bf(x1.w);
            *(short8*)(&As[am][ak]) = a8;
        }
        // ---- stage B transposed: Bs[n][k] = W[k0+k][nbase+n]
        {
            const float* wb = W + (size_t)(k0 + bk0) * 1024 + nbase + bn;
            short8 b8;
#pragma unroll
            for (int j = 0; j < 8; ++j) b8[j] = (short)f2bf(wb[(size_t)j * 1024]);
            *(short8*)(&Bs[bn][bk0]) = b8;
        }
        __syncthreads();

        // ---- MFMA: one 16x16x32 per C-tile
        short8 af = *(const short8*)(&As[wave * 16 + l15][quad * 8]);
#pragma unroll
        for (int ct = 0; ct < 4; ++ct) {
            short8 bf = *(const short8*)(&Bs[ct * 16 + l15][quad * 8]);
            acc[ct] = __builtin_amdgcn_mfma_f32_16x16x32_bf16(af, bf, acc[ct], 0, 0, 0);
        }
    }

    // ---- epilogue: bias, bf16, scatter to head layout
    // C/D layout: col = lane&15, row = quad*4 + reg   [m89/m91 verified]
#pragma unroll
    for (int ct = 0; ct < 4; ++ct) {
        const int n = nbase + ct * 16 + l15;
        const int h = n >> 6, d = n & 63;
        const float bval = bias[n];
#pragma unroll
        for (int r = 0; r < 4; ++r) {
            const int gm = mbase + wave * 16 + quad * 4 + r;
            const int b = gm >> 11, s = gm & 2047;
            const int bh = b * 16 + h;
            const unsigned short hv = f2bf(acc[ct][r] + bval);
            if (z < 2) out[((size_t)bh * 2048 + s) * 64 + d] = hv;     // [B,H,S,DK]
            else       out[((size_t)bh * 64 + d) * 2048 + s] = hv;     // [B,H,DK,S]
        }
    }
}

// ---------------------------------------------------------------------------
// Kernel 2: flash attention.  grid = (32 q-tiles, 32 b*h).  4 waves/block,
// each wave owns 16 q-rows.  Q A-frags in registers; K and V B-frags loaded
// directly from global (V pre-transposed).  P converted C-layout -> A-layout
// through a per-wave padded LDS tile.  Writes pre-LN x [B,S,D] fp32 to ws.
// ---------------------------------------------------------------------------
__global__ __launch_bounds__(256) void attn(
    const unsigned short* __restrict__ qb, const unsigned short* __restrict__ kb,
    const unsigned short* __restrict__ vtb, float* __restrict__ xw)
{
    const int tid  = threadIdx.x;
    const int wave = tid >> 6;
    const int lane = tid & 63;
    const int l15  = lane & 15;
    const int quad = lane >> 4;

    const int bh    = blockIdx.y;
    const int qbase = blockIdx.x * 64 + wave * 16;

    // Q A-fragments (m = l15, k = quad*8+j), held for the whole K loop
    const unsigned short* Qp = qb + ((size_t)bh * 2048 + qbase + l15) * 64 + quad * 8;
    const short8 qf0 = *(const short8*)(Qp);
    const short8 qf1 = *(const short8*)(Qp + 32);

    const unsigned short* Kbh = kb + (size_t)bh * 2048 * 64;   // [S][DK]
    const unsigned short* Vbh = vtb + (size_t)bh * 64 * 2048;  // [DK][S]

    float m_r[4] = {-3.0e38f, -3.0e38f, -3.0e38f, -3.0e38f};
    float l_r[4] = {0.f, 0.f, 0.f, 0.f};
    f32x4 O[4]   = {{0.f,0.f,0.f,0.f},{0.f,0.f,0.f,0.f},{0.f,0.f,0.f,0.f},{0.f,0.f,0.f,0.f}};

    __shared__ unsigned short Pt[4][16][40];   // per-wave P tile, padded

    const float SC = 0.125f * 1.44269504089f;  // 1/sqrt(DK) folded into exp2

    for (int kt = 0; kt < 2048; kt += 32) {
        // ---- scores: S[16q][32k] as two 16x16 C-tiles
        f32x4 sc[2];
#pragma unroll
        for (int ct = 0; ct < 2; ++ct) {
            const unsigned short* Kp = Kbh + (size_t)(kt + ct * 16 + l15) * 64 + quad * 8;
            f32x4 a = {0.f, 0.f, 0.f, 0.f};
            a = __builtin_amdgcn_mfma_f32_16x16x32_bf16(qf0, *(const short8*)Kp,        a, 0, 0, 0);
            a = __builtin_amdgcn_mfma_f32_16x16x32_bf16(qf1, *(const short8*)(Kp + 32), a, 0, 0, 0);
            sc[ct] = a;
        }

        // ---- online softmax per q-row (row = quad*4+r spans the 16-lane col group)
        float alpha[4], p0[4], p1[4];
#pragma unroll
        for (int r = 0; r < 4; ++r) {
            float mx = fmaxf(sc[0][r], sc[1][r]);
#pragma unroll
            for (int off = 8; off >= 1; off >>= 1) mx = fmaxf(mx, __shfl_xor(mx, off));
            const float mn = fmaxf(m_r[r], mx);
            alpha[r] = exp2f((m_r[r] - mn) * SC);
            m_r[r] = mn;
            p0[r] = exp2f((sc[0][r] - mn) * SC);
            p1[r] = exp2f((sc[1][r] - mn) * SC);
            float rs = p0[r] + p1[r];
#pragma unroll
            for (int off = 8; off >= 1; off >>= 1) rs += __shfl_xor(rs, off);
            l_r[r] = alpha[r] * l_r[r] + rs;
        }

        // ---- P: C-layout -> A-layout via LDS round-trip
        __syncthreads();
#pragma unroll
        for (int r = 0; r < 4; ++r) {
            Pt[wave][quad * 4 + r][l15]      = f2bf(p0[r]);
            Pt[wave][quad * 4 + r][16 + l15] = f2bf(p1[r]);
        }
        __syncthreads();
        const short8 pf = *(const short8*)(&Pt[wave][l15][quad * 8]);

        // ---- O = O*alpha + P @ V   (V B-frags straight from global, [DK][S])
#pragma unroll
        for (int ct4 = 0; ct4 < 4; ++ct4) {
#pragma unroll
            for (int r = 0; r < 4; ++r) O[ct4][r] *= alpha[r];
            const unsigned short* Vp = Vbh + (size_t)(ct4 * 16 + l15) * 2048 + kt + quad * 8;
            O[ct4] = __builtin_amdgcn_mfma_f32_16x16x32_bf16(pf, *(const short8*)Vp, O[ct4], 0, 0, 0);
        }
    }

    // ---- normalize and write pre-LN x[B,S,D] fp32
    const int b = bh >> 4, h = bh & 15;
#pragma unroll
    for (int ct4 = 0; ct4 < 4; ++ct4) {
#pragma unroll
        for (int r = 0; r < 4; ++r) {
            const int s = qbase + quad * 4 + r;
            xw[((size_t)b * 2048 + s) * 1024 + h * 64 + ct4 * 16 + l15] = O[ct4][r] / l_r[r];
        }
    }
}

// ---------------------------------------------------------------------------
// Kernel 3: residual + LayerNorm (eps = 1e-6).  One block per (b,s) row.
// ---------------------------------------------------------------------------
__global__ __launch_bounds__(256) void ln_kernel(
    const float* __restrict__ xw, const float* __restrict__ res,
    const float* __restrict__ gamma, const float* __restrict__ beta,
    float* __restrict__ out)
{
    const int row = blockIdx.x;
    const int tid = threadIdx.x;
    const size_t base = (size_t)row * 1024 + tid * 4;

    const float4 x  = *(const float4*)(xw + base);
    const float4 rv = *(const float4*)(res + base);
    float4 y;
    y.x = x.x + rv.x; y.y = x.y + rv.y; y.z = x.z + rv.z; y.w = x.w + rv.w;

    float s  = y.x + y.y + y.z + y.w;
    float s2 = y.x * y.x + y.y * y.y + y.z * y.z + y.w * y.w;
#pragma unroll
    for (int off = 32; off >= 1; off >>= 1) {
        s  += __shfl_xor(s, off);
        s2 += __shfl_xor(s2, off);
    }
    __shared__ float red[8];
    const int wave = tid >> 6;
    if ((tid & 63) == 0) { red[wave] = s; red[4 + wave] = s2; }
    __syncthreads();
    s  = red[0] + red[1] + red[2] + red[3];
    s2 = red[4] + red[5] + red[6] + red[7];

    const float mu   = s * (1.0f / 1024.0f);
    const float var  = s2 * (1.0f / 1024.0f) - mu * mu;
    const float rstd = rsqrtf(var + 1e-6f);

    const float4 g  = *(const float4*)(gamma + tid * 4);
    const float4 bt = *(const float4*)(beta + tid * 4);
    float4 o;
    o.x = (y.x - mu) * rstd * g.x + bt.x;
    o.y = (y.y - mu) * rstd * g.y + bt.y;
    o.z = (y.z - mu) * rstd * g.z + bt.z;
    o.w = (y.w - mu) * rstd * g.w + bt.w;
    *(float4*)(out + base) = o;
}

// ---------------------------------------------------------------------------
extern "C" void kernel_launch(void* const* d_in, const int* in_sizes, int n_in,
                              void* d_out, int out_size, void* d_ws, size_t ws_size,
                              hipStream_t stream) {
    const float* query = (const float*)d_in[0];
    const float* key_  = (const float*)d_in[1];
    const float* value = (const float*)d_in[2];
    const float* Wq    = (const float*)d_in[3];
    const float* bq    = (const float*)d_in[4];
    const float* Wk    = (const float*)d_in[5];
    const float* bk    = (const float*)d_in[6];
    const float* Wv    = (const float*)d_in[7];
    const float* bv    = (const float*)d_in[8];
    const float* ln_g  = (const float*)d_in[9];
    const float* ln_b  = (const float*)d_in[10];
    float* out = (float*)d_out;

    // workspace: Q bf16 8MB | K bf16 8MB | V^T bf16 8MB | x fp32 16MB = 40MB
    char* ws = (char*)d_ws;
    unsigned short* qb  = (unsigned short*)(ws);
    unsigned short* kb  = (unsigned short*)(ws + (size_t)8  * 1024 * 1024);
    unsigned short* vtb = (unsigned short*)(ws + (size_t)16 * 1024 * 1024);
    float*          xwp = (float*)        (ws + (size_t)24 * 1024 * 1024);

    qkv_gemm<<<dim3(64, 16, 3), 256, 0, stream>>>(
        query, key_, value, Wq, Wk, Wv, bq, bk, bv, qb, kb, vtb);
    attn<<<dim3(32, 32), 256, 0, stream>>>(qb, kb, vtb, xwp);
    ln_kernel<<<4096, 256, 0, stream>>>(xwp, query, ln_g, ln_b, out);
}